// Round 3
// baseline (431.742 us; speedup 1.0000x reference)
//
#include <hip/hip_runtime.h>
#include <hip/hip_bf16.h>

// SplineCNN block.
// Edge data (CSR(dst) order), produced by basis_fill:
//   g_ebas[slot] = DENSE 32-bin bf16 basis row (64 B; bins 27..31 = 0).
//     Dense is valid because the 8 widx of one edge are provably distinct
//     (per-dim (lo+0)%3 != (lo+1)%3), so scatter-add == assignment.
//   g_esrc[slot] = src node id.
// This hoists the per-edge bin-match loop (8 iter x ~10 VALU, formerly run
// per conv per chunk = 35% VALUBusy in fused_conv3) out of all three convs:
// phase 1 now loads B-fragments directly (2 scalar bf16 loads per lane-j).
// No LDS record staging, no s_waitcnt(0) drain in the conv hot path.
// conv1/conv2: 512 thr / 8 nodes, wave-per-node phase-1 scatter-GEMM
//   (K-slot kidx = j*4 + quad, early-exit jmax = ceil(cnt/4)); S bf16
//   (pitch 904); phase 2 dense MFMA GEMM vs packed weights.
// conv3: same scheme, CIN=96: 6 A-tiles x 2 B-tiles phase 1; phase 2
//   K=2688 GEMM split 4-way over waves (21 K-tiles each), LDS reduction;
//   kq=3 waves own root tiles + epilogue.
// Scan: two-level parallel (196-block partial + top + add).

#define EPS 1e-5f
#define MAXN 50176
#define MAXE 401408
#define SP2 904    // bf16 elems per S row (conv1/2): 864 spline + 32 root + 8 pad
#define SP3 2696   // bf16 elems per S row (conv3): 2592 spline + 96 root + 8 pad

typedef __attribute__((ext_vector_type(8))) short short8;
typedef __attribute__((ext_vector_type(4))) float floatx4;

__device__ int             g_deg[MAXN];
__device__ int             g_offs[MAXN + 1];
__device__ int             g_cursor[MAXN];
__device__ int             g_bsum[256];
__device__ int             g_esrc[MAXE];
__device__ __align__(16) uint4 g_ebas[MAXE * 4];   // dense 32-bin bf16 rows
__device__ __align__(16) __hip_bfloat16 g_h0[MAXN * 32];
__device__ __align__(16) __hip_bfloat16 g_h1[MAXN * 32];
__device__ __align__(16) __hip_bfloat16 g_h2[MAXN * 64];
__device__ __align__(16) __hip_bfloat16 g_h3[MAXN * 96];
__device__ __align__(16) __hip_bfloat16 g_Wp1[28672];
__device__ __align__(16) __hip_bfloat16 g_Wp2[57344];
__device__ __align__(16) __hip_bfloat16 g_Wp3[86016];
__device__ float           g_stats[128];
__device__ int             g_isbf16;

__device__ __forceinline__ float loadf(const void* p, int i, bool bf)
{
    return bf ? (float)((const __hip_bfloat16*)p)[i] : ((const float*)p)[i];
}
__device__ __forceinline__ float bf16f(unsigned int u)
{
    return __uint_as_float(u << 16);
}
__device__ __forceinline__ unsigned short bfbits(float f)
{
    union { __hip_bfloat16 h; unsigned short u; } cv;
    cv.h = __float2bfloat16(f);
    return cv.u;
}

// ---------------- K1: zero-init scratch + wire dtype detect ----------------
__global__ void init_detect(const unsigned int* __restrict__ x, int n)
{
    int i = blockIdx.x * blockDim.x + threadIdx.x;
    if (blockIdx.x == 0 && threadIdx.x < 64) {
        int lane = threadIdx.x;
        int cnt = 0;
        for (int k = lane; k < 256; k += 64) {
            unsigned int lo = x[k] & 0xFFFFu;
            int ex = (int)((lo >> 7) & 0xFFu);
            if (lo == 0u || (ex >= 96 && ex <= 140)) cnt++;
        }
#pragma unroll
        for (int o = 1; o < 64; o <<= 1) cnt += __shfl_xor(cnt, o, 64);
        if (lane == 0) g_isbf16 = (cnt >= 200) ? 1 : 0;
    }
    if (i < n) { g_deg[i] = 0; g_cursor[i] = 0; }
    if (i < 128) g_stats[i] = 0.0f;
}

// ---------------- weight pack helpers (device) ----------------
template <int COUT>
__device__ __forceinline__ void prep_ws_dev(const void* W, const void* root,
                                            __hip_bfloat16* Wp, int t, bool bf)
{
    int j = t & 7;
    int lane = (t >> 3) & 63;
    int rest = t >> 9;
    int kk = rest % 28;
    int nt = rest / 28;
    int k = kk * 32 + (lane >> 4) * 8 + j;
    int o = nt * 16 + (lane & 15);
    float v = (k < 864) ? loadf(W, k * COUT + o, bf)
                        : loadf(root, (k - 864) * COUT + o, bf);
    Wp[t] = __float2bfloat16(v);
}

// conv3 pack: K axis = bin*96 + ch (2592 spline) then 96 root channels.
// B-fragment layout matches phase-2 read: t = ((nt*84+kk)*64+lane)*8 + j,
// element k = kk*32 + quad*8 + j, col o = nt*16 + m. Channels 67..95 are 0
// (h3 pads 64 BN-ELU ch + 3 pos ch to 96).
__device__ __forceinline__ void prep_w3_dev(const void* W, const void* root,
                                            __hip_bfloat16* Wp, int t, bool bf)
{
    const int KB = 84;
    int j = t & 7;
    int lane = (t >> 3) & 63;
    int rest = t >> 9;          // < 168
    int kk = rest % KB;         // 0..83
    int nt = rest / KB;         // 0..1
    int k = kk * 32 + (lane >> 4) * 8 + j;   // 0..2687
    int o = nt * 16 + (lane & 15);           // 0..31
    float v = 0.0f;
    if (k < 2592) {
        int bin = k / 96;
        int ch = k - bin * 96;
        if (ch < 67) v = loadf(W, (bin * 67 + ch) * 32 + o, bf);
    } else {
        int ch = k - 2592;
        if (ch < 67) v = loadf(root, ch * 32 + o, bf);
    }
    Wp[t] = __float2bfloat16(v);
}

// ---------------- K2: degree count + cast x + pack all weights ----------------
__global__ void misc_kernel(const int* __restrict__ dst, const void* __restrict__ x,
                            const void* W1, const void* r1,
                            const void* W2, const void* r2,
                            const void* W3, const void* r3, int E, int N)
{
    int t = blockIdx.x * blockDim.x + threadIdx.x;
    const bool bf = (g_isbf16 != 0);
    if (t < E) { atomicAdd(&g_deg[dst[t]], 1); return; }
    t -= E;
    int nx = N * 32;
    if (t < nx) { g_h0[t] = __float2bfloat16(loadf(x, t, bf)); return; }
    t -= nx;
    if (t < 28672) { prep_ws_dev<32>(W1, r1, g_Wp1, t, bf); return; }
    t -= 28672;
    if (t < 57344) { prep_ws_dev<64>(W2, r2, g_Wp2, t, bf); return; }
    t -= 57344;
    if (t < 86016) { prep_w3_dev(W3, r3, g_Wp3, t, bf); return; }
}

// ---------------- K3a: per-block scan (256 elems/block) ----------------
__global__ void scan_blk(int n)
{
    __shared__ int buf[256];
    int tid = threadIdx.x;
    int i = blockIdx.x * 256 + tid;
    int v = (i < n) ? g_deg[i] : 0;
    buf[tid] = v;
    __syncthreads();
    for (int o = 1; o < 256; o <<= 1) {
        int t = (tid >= o) ? buf[tid - o] : 0;
        __syncthreads();
        buf[tid] += t;
        __syncthreads();
    }
    if (i < n) g_offs[i] = buf[tid] - v;   // block-local exclusive
    if (tid == 255) g_bsum[blockIdx.x] = buf[255];
}

// ---------------- K3b: scan of block sums (1 block; nb <= 256) ----------------
__global__ void scan_top(int nb, int n)
{
    __shared__ int buf[256];
    int tid = threadIdx.x;
    int v = (tid < nb) ? g_bsum[tid] : 0;
    buf[tid] = v;
    __syncthreads();
    for (int o = 1; o < 256; o <<= 1) {
        int t = (tid >= o) ? buf[tid - o] : 0;
        __syncthreads();
        buf[tid] += t;
        __syncthreads();
    }
    if (tid < nb) g_bsum[tid] = buf[tid] - v;   // exclusive
    if (tid == nb - 1) g_offs[n] = buf[tid];    // total = E
}

// ---------------- K3c: add block offsets ----------------
__global__ void scan_add(int n)
{
    int i = blockIdx.x * 256 + threadIdx.x;
    if (i < n) g_offs[i] += g_bsum[i >> 8];
}

// ---------------- K4: basis + CSR fill (dense 64-B basis rows) ----------------
__global__ void basis_fill(const void* __restrict__ attr,
                           const int* __restrict__ src,
                           const int* __restrict__ dst, int E)
{
    int e = blockIdx.x * blockDim.x + threadIdx.x;
    if (e >= E) return;
    const bool bf = (g_isbf16 != 0);
    float f[3];
    int lo[3];
#pragma unroll
    for (int d = 0; d < 3; ++d) {
        float a = loadf(attr, e * 3 + d, bf);
        float s = a * 3.0f;
        float l = floorf(s);
        lo[d] = (int)l;
        f[d] = s - l;
    }
    const int p3[3] = {1, 3, 9};
    int wx8[8];
    unsigned short bb[8];
#pragma unroll
    for (int b = 0; b < 8; ++b) {
        float w = 1.0f;
        int id = 0;
#pragma unroll
        for (int d = 0; d < 3; ++d) {
            int bit = (b >> d) & 1;
            w *= bit ? f[d] : (1.0f - f[d]);
            id += ((lo[d] + bit) % 3) * p3[d];
        }
        wx8[b] = id;
        bb[b] = bfbits(w);
    }
    // densify: 16 u32 words = 32 bf16 bins (8 distinct wx -> pure assignment)
    unsigned wds[16];
#pragma unroll
    for (int i = 0; i < 16; ++i) {
        unsigned w = 0;
#pragma unroll
        for (int b = 0; b < 8; ++b) {
            if (wx8[b] == 2 * i)     w |= (unsigned)bb[b];
            if (wx8[b] == 2 * i + 1) w |= (unsigned)bb[b] << 16;
        }
        wds[i] = w;
    }
    int d = dst[e];
    int p = atomicAdd(&g_cursor[d], 1);
    int slot = g_offs[d] + p;
    uint4* out4 = &g_ebas[(size_t)slot * 4];
    out4[0] = make_uint4(wds[0],  wds[1],  wds[2],  wds[3]);
    out4[1] = make_uint4(wds[4],  wds[5],  wds[6],  wds[7]);
    out4[2] = make_uint4(wds[8],  wds[9],  wds[10], wds[11]);
    out4[3] = make_uint4(wds[12], wds[13], wds[14], wds[15]);
    g_esrc[slot] = src[e];
}

// ---------------- fused conv (CIN=32), 8 nodes / 512 thr ----------------
// IN_SEL: 0 = g_h0, 1 = g_h1.  OUT_SEL: 1 = g_h1 (+ELU), 2 = g_h2 (raw).
template <int COUT, bool ELU, int IN_SEL, int OUT_SEL>
__global__ __launch_bounds__(512, 8) void fused_conv(const void* __restrict__ bias,
                                                     int N)
{
    __shared__ unsigned short Sb[8 * SP2];
    __shared__ float invd[8];
    int tid = threadIdx.x, wid = tid >> 6, lane = tid & 63;
    int nbase = blockIdx.x * 8;
    const bool bf = (g_isbf16 != 0);
    const unsigned short* xptr = (IN_SEL == 0) ? (const unsigned short*)g_h0
                                               : (const unsigned short*)g_h1;
    const __hip_bfloat16* Wp = (COUT == 32) ? g_Wp1 : g_Wp2;

    int n = nbase + wid;
    int m = lane & 15, quad = lane >> 4;

    // ---- phase 1: wave wid builds S row for its node via MFMA scatter-GEMM ----
    if (n < N) {
        int e0 = g_offs[n], e1 = g_offs[n + 1];
        floatx4 C00 = {}, C01 = {}, C10 = {}, C11 = {};
        for (int base = e0; base < e1; base += 32) {
            int cnt = e1 - base; if (cnt > 32) cnt = 32;
            int jmax = (cnt + 3) >> 2;   // wave-uniform; K-slots >= cnt are zeros
            unsigned a0w[4] = {0, 0, 0, 0}, a1w[4] = {0, 0, 0, 0};
            unsigned b0w[4] = {0, 0, 0, 0}, b1w[4] = {0, 0, 0, 0};
#pragma unroll
            for (int j = 0; j < 8; ++j) {
                if (j >= jmax) break;
                // K-permutation: fragment slot (quad, j) holds edge j*4+quad.
                int kidx = j * 4 + quad;
                int e = base + kidx;
                int sn = 0;
                unsigned p0 = 0, p1 = 0;
                if (kidx < cnt) {
                    sn = g_esrc[e];
                    const unsigned short* brow =
                        (const unsigned short*)&g_ebas[(size_t)e * 4];
                    p0 = brow[m];
                    p1 = brow[16 + m];
                }
                // sn==0 when masked: A value arbitrary, B = 0 -> contributes 0
                unsigned av0 = xptr[(size_t)sn * 32 + m];
                unsigned av1 = xptr[(size_t)sn * 32 + 16 + m];
                unsigned sh = 16 * (j & 1);
                a0w[j >> 1] |= av0 << sh;
                a1w[j >> 1] |= av1 << sh;
                b0w[j >> 1] |= p0 << sh;
                b1w[j >> 1] |= p1 << sh;
            }
            union U { unsigned w[4]; short8 v; } A0, A1, B0, B1;
#pragma unroll
            for (int q = 0; q < 4; ++q) {
                A0.w[q] = a0w[q]; A1.w[q] = a1w[q];
                B0.w[q] = b0w[q]; B1.w[q] = b1w[q];
            }
            C00 = __builtin_amdgcn_mfma_f32_16x16x32_bf16(A0.v, B0.v, C00, 0, 0, 0);
            C01 = __builtin_amdgcn_mfma_f32_16x16x32_bf16(A0.v, B1.v, C01, 0, 0, 0);
            C10 = __builtin_amdgcn_mfma_f32_16x16x32_bf16(A1.v, B0.v, C10, 0, 0, 0);
            C11 = __builtin_amdgcn_mfma_f32_16x16x32_bf16(A1.v, B1.v, C11, 0, 0, 0);
        }
        // writeback: C[mt][nt] lane holds col=m (bin-in-tile), rows quad*4+r (ch)
        unsigned short* Srow = Sb + wid * SP2;
        {
            floatx4 Cf[4] = {C00, C01, C10, C11};
#pragma unroll
            for (int f = 0; f < 4; ++f) {
                int mt = f >> 1, nt = f & 1;
                int bin = nt * 16 + m;
                if (bin < 27) {
                    union { unsigned short h[4]; uint2 u; } pk;
#pragma unroll
                    for (int r = 0; r < 4; ++r) pk.h[r] = bfbits(Cf[f][r]);
                    *(uint2*)(Srow + bin * 32 + mt * 16 + quad * 4) = pk.u;
                }
            }
        }
        if (lane < 32) Srow[864 + lane] = xptr[(size_t)n * 32 + lane];
        if (lane == 0) {
            int deg = e1 - e0;
            invd[wid] = 1.0f / (float)(deg < 1 ? 1 : deg);
        }
    }
    __syncthreads();

    // ---- phase 2: wave w = col-tile w of GEMM 16 x 896 @ 896 x COUT ----
    if (wid * 16 < COUT) {
        int mrow = m & 7;   // 8 nodes; rows 8..15 duplicate (discarded below)
        const unsigned short* Ab = Sb + mrow * SP2 + quad * 8;
        floatx4 accS = {}, accR = {};
#pragma unroll
        for (int kk = 0; kk < 28; ++kk) {
            short8 a = *(const short8*)(Ab + kk * 32);
            const short* bp = (const short*)Wp +
                ((size_t)(wid * 28 + kk) * 64 + lane) * 8;
            short8 b = *(const short8*)bp;
            if (kk < 27) accS = __builtin_amdgcn_mfma_f32_16x16x32_bf16(a, b, accS, 0, 0, 0);
            else         accR = __builtin_amdgcn_mfma_f32_16x16x32_bf16(a, b, accR, 0, 0, 0);
        }
        int o = wid * 16 + m;
        float bval = loadf(bias, o, bf);
#pragma unroll
        for (int r = 0; r < 4; ++r) {
            int slot = quad * 4 + r;
            if (slot >= 8) continue;
            int nn = nbase + slot;
            if (nn >= N) continue;
            float v = accS[r] * invd[slot] + accR[r] + bval;
            if (ELU) v = v > 0.0f ? v : expm1f(v);
            if (OUT_SEL == 1) g_h1[nn * 32 + o] = __float2bfloat16(v);
            else              g_h2[nn * 64 + o] = __float2bfloat16(v);
        }
    }
}

// ---------------- fused conv3 (CIN=96 from g_h3, COUT=32 to out) ----------------
// Phase 1: 6 A-tiles x 2 B-tiles. Phase 2: 16 x 2688 @ 2688 x 32 GEMM, K split
// 4-way over waves (21 K-tiles each), LDS reduction; kq==3 waves hold root
// tiles (kk 81..83, never invd-scaled) and run the epilogue + final store.
__global__ __launch_bounds__(512, 4) void fused_conv3(const void* __restrict__ bias,
                                                      void* __restrict__ out_ext,
                                                      int N)
{
    __shared__ __align__(16) unsigned short Sb[8 * SP3];   // 43136 B
    __shared__ float red[6][64][4];                        // 6144 B
    __shared__ float invd[8];
    int tid = threadIdx.x, wid = tid >> 6, lane = tid & 63;
    int nbase = blockIdx.x * 8;
    const bool bf = (g_isbf16 != 0);
    const unsigned short* xptr = (const unsigned short*)g_h3;

    int n = nbase + wid;
    int m = lane & 15, quad = lane >> 4;

    // ---- phase 1: wave wid builds S row (27 bins x 96 ch) via MFMA scatter ----
    if (n < N) {
        int e0 = g_offs[n], e1 = g_offs[n + 1];
        floatx4 C[6][2];
#pragma unroll
        for (int t = 0; t < 6; ++t) {
            C[t][0] = (floatx4){0.f, 0.f, 0.f, 0.f};
            C[t][1] = (floatx4){0.f, 0.f, 0.f, 0.f};
        }
        for (int base = e0; base < e1; base += 32) {
            int cnt = e1 - base; if (cnt > 32) cnt = 32;
            int jmax = (cnt + 3) >> 2;
            unsigned aw[6][4] = {{0, 0, 0, 0}, {0, 0, 0, 0}, {0, 0, 0, 0},
                                 {0, 0, 0, 0}, {0, 0, 0, 0}, {0, 0, 0, 0}};
            unsigned b0w[4] = {0, 0, 0, 0}, b1w[4] = {0, 0, 0, 0};
#pragma unroll
            for (int j = 0; j < 8; ++j) {
                if (j >= jmax) break;
                int kidx = j * 4 + quad;
                int e = base + kidx;
                int sn = 0;
                unsigned p0 = 0, p1 = 0;
                if (kidx < cnt) {
                    sn = g_esrc[e];
                    const unsigned short* brow =
                        (const unsigned short*)&g_ebas[(size_t)e * 4];
                    p0 = brow[m];
                    p1 = brow[16 + m];
                }
                const unsigned short* hr = xptr + (size_t)sn * 96 + m;
                unsigned av[6];
#pragma unroll
                for (int t = 0; t < 6; ++t) av[t] = hr[t * 16];
                unsigned sh = 16 * (j & 1);
#pragma unroll
                for (int t = 0; t < 6; ++t) aw[t][j >> 1] |= av[t] << sh;
                b0w[j >> 1] |= p0 << sh;
                b1w[j >> 1] |= p1 << sh;
            }
            union U { unsigned w[4]; short8 v; } A, B0, B1;
#pragma unroll
            for (int q = 0; q < 4; ++q) { B0.w[q] = b0w[q]; B1.w[q] = b1w[q]; }
#pragma unroll
            for (int t = 0; t < 6; ++t) {
#pragma unroll
                for (int q = 0; q < 4; ++q) A.w[q] = aw[t][q];
                C[t][0] = __builtin_amdgcn_mfma_f32_16x16x32_bf16(A.v, B0.v, C[t][0], 0, 0, 0);
                C[t][1] = __builtin_amdgcn_mfma_f32_16x16x32_bf16(A.v, B1.v, C[t][1], 0, 0, 0);
            }
        }
        // writeback: C[t][nt] lane holds col=m (bin-in-tile), rows quad*4+r
        // (ch-in-tile) -> S[bin*96 + t*16 + quad*4 + r]
        unsigned short* Srow = Sb + wid * SP3;
#pragma unroll
        for (int t = 0; t < 6; ++t) {
#pragma unroll
            for (int ntile = 0; ntile < 2; ++ntile) {
                int bin = ntile * 16 + m;
                if (bin < 27) {
                    union { unsigned short h[4]; uint2 uu; } pk;
#pragma unroll
                    for (int r = 0; r < 4; ++r) pk.h[r] = bfbits(C[t][ntile][r]);
                    *(uint2*)(Srow + bin * 96 + t * 16 + quad * 4) = pk.uu;
                }
            }
        }
        for (int t2 = lane; t2 < 96; t2 += 64)
            Srow[2592 + t2] = xptr[(size_t)n * 96 + t2];
        if (lane == 0) {
            int deg = e1 - e0;
            invd[wid] = 1.0f / (float)(deg < 1 ? 1 : deg);
        }
    }
    __syncthreads();

    // ---- phase 2: GEMM 16 x 2688 @ 2688 x 32; wave = (col-tile nt, K-quarter kq)
    int nt = wid & 1, kq = wid >> 1;
    int mrow = m & 7;   // 8 nodes; rows 8..15 duplicate (discarded in epilogue)
    const unsigned short* Ab = Sb + mrow * SP3 + quad * 8;
    floatx4 accS = {}, accR = {};
    {
        int kbeg = kq * 21, kend = kbeg + 21;
        int ksplit = (kend < 81) ? kend : 81;   // root tiles are kk 81..83 (kq==3)
        for (int kk = kbeg; kk < ksplit; ++kk) {
            short8 a = *(const short8*)(Ab + kk * 32);
            const short* bp = (const short*)g_Wp3 +
                ((size_t)(nt * 84 + kk) * 64 + lane) * 8;
            short8 b = *(const short8*)bp;
            accS = __builtin_amdgcn_mfma_f32_16x16x32_bf16(a, b, accS, 0, 0, 0);
        }
        for (int kk = ksplit; kk < kend; ++kk) {
            short8 a = *(const short8*)(Ab + kk * 32);
            const short* bp = (const short*)g_Wp3 +
                ((size_t)(nt * 84 + kk) * 64 + lane) * 8;
            short8 b = *(const short8*)bp;
            accR = __builtin_amdgcn_mfma_f32_16x16x32_bf16(a, b, accR, 0, 0, 0);
        }
    }
    if (kq < 3)
        *(floatx4*)&red[wid][lane][0] = accS;
    __syncthreads();
    if (kq == 3) {
#pragma unroll
        for (int w = 0; w < 3; ++w)
            accS += *(const floatx4*)&red[2 * w + nt][lane][0];
        int o = nt * 16 + m;
        float bval = loadf(bias, o, bf);
#pragma unroll
        for (int r = 0; r < 4; ++r) {
            int slot = quad * 4 + r;
            if (slot >= 8) continue;
            int nn = nbase + slot;
            if (nn >= N) continue;
            float v = accS[r] * invd[slot] + accR[r] + bval;
            if (bf) ((__hip_bfloat16*)out_ext)[nn * 32 + o] = __float2bfloat16(v);
            else    ((float*)out_ext)[nn * 32 + o] = v;
        }
    }
}

// ---------------- BN stats (reads g_h2) ----------------
__global__ void bn_reduce(int n)
{
    int tid = threadIdx.x;
    int c = tid & 63;
    int r = tid >> 6;
    float s = 0.0f, s2 = 0.0f;
    for (int i = blockIdx.x * 4 + r; i < n; i += gridDim.x * 4) {
        float v = (float)g_h2[i * 64 + c];
        s += v; s2 += v * v;
    }
    __shared__ float b1s[256], b2s[256];
    b1s[tid] = s; b2s[tid] = s2;
    __syncthreads();
    if (r == 0) {
        s  = b1s[c] + b1s[c + 64] + b1s[c + 128] + b1s[c + 192];
        s2 = b2s[c] + b2s[c + 64] + b2s[c + 128] + b2s[c + 192];
        atomicAdd(&g_stats[c], s);
        atomicAdd(&g_stats[64 + c], s2);
    }
}

// ---------------- h3 = [elu(bn(h2)), pos, 0-pad] (96 ch), coef inline -------
__global__ void h3_build(const void* __restrict__ pos,
                         const void* __restrict__ gamma,
                         const void* __restrict__ beta, int N)
{
    __shared__ float cf[128];
    int t = threadIdx.x;
    const bool bf = (g_isbf16 != 0);
    if (t < 64) {
        float inv_n = 1.0f / (float)N;
        float mu = g_stats[t] * inv_n;
        float var = g_stats[64 + t] * inv_n - mu * mu;
        float A = rsqrtf(var + EPS) * loadf(gamma, t, bf);
        cf[t] = A;
        cf[64 + t] = loadf(beta, t, bf) - mu * A;
    }
    __syncthreads();
    int idx = blockIdx.x * blockDim.x + t;
    if (idx >= N * 96) return;
    int n = idx / 96, ch = idx - n * 96;
    float v;
    if (ch < 64) {
        float h = (float)g_h2[n * 64 + ch];
        v = h * cf[ch] + cf[64 + ch];
        v = v > 0.0f ? v : expm1f(v);
    } else if (ch < 67) {
        v = loadf(pos, n * 3 + (ch - 64), bf);
    } else {
        v = 0.0f;
    }
    g_h3[(size_t)n * 96 + ch] = __float2bfloat16(v);
}

extern "C" void kernel_launch(void* const* d_in, const int* in_sizes, int n_in,
                              void* d_out, int out_size, void* d_ws, size_t ws_size,
                              hipStream_t stream)
{
    const void* x      = d_in[0];
    const int*  eindex = (const int*)d_in[1];
    const void* eattr  = d_in[2];
    const void* pos    = d_in[3];
    const void* W1     = d_in[4];
    const void* root1  = d_in[5];
    const void* b1     = d_in[6];
    const void* W2     = d_in[7];
    const void* root2  = d_in[8];
    const void* b2     = d_in[9];
    const void* gamma  = d_in[10];
    const void* beta   = d_in[11];
    const void* W3     = d_in[12];
    const void* root3  = d_in[13];
    const void* b3     = d_in[14];
    (void)d_ws; (void)ws_size; (void)n_in; (void)out_size;

    const int N = in_sizes[0] / 32;
    const int E = in_sizes[1] / 2;
    const int* srcp = eindex;
    const int* dstp = eindex + E;

    init_detect<<<(N + 255) / 256, 256, 0, stream>>>((const unsigned int*)x, N);
    {
        int tot = E + N * 32 + 28672 + 57344 + 86016;
        misc_kernel<<<(tot + 255) / 256, 256, 0, stream>>>(
            dstp, x, W1, root1, W2, root2, W3, root3, E, N);
    }
    // two-level parallel scan
    int nb = (N + 255) / 256;   // 196 <= 256
    scan_blk<<<nb, 256, 0, stream>>>(N);
    scan_top<<<1, 256, 0, stream>>>(nb, N);
    scan_add<<<nb, 256, 0, stream>>>(N);
    basis_fill<<<(E + 255) / 256, 256, 0, stream>>>(eattr, srcp, dstp, E);

    int nb8 = (N + 7) / 8;
    fused_conv<32, true, 0, 1><<<nb8, 512, 0, stream>>>(b1, N);
    fused_conv<64, false, 1, 2><<<nb8, 512, 0, stream>>>(b2, N);
    bn_reduce<<<120, 256, 0, stream>>>(N);
    h3_build<<<(N * 96 + 255) / 256, 256, 0, stream>>>(pos, gamma, beta, N);
    fused_conv3<<<nb8, 512, 0, stream>>>(b3, d_out, N);
}

// Round 4
// 371.132 us; speedup vs baseline: 1.1633x; 1.1633x over previous
//
#include <hip/hip_runtime.h>
#include <hip/hip_bf16.h>

// SplineCNN block.
// Edge data (CSR(dst) order), produced by basis_fill:
//   g_ebas[slot] = dense 32-bin bf16 basis row, PAIR-INTERLEAVED: u32 word i
//     holds (bin i, bin i+16). Dense is valid because the 8 widx of one edge
//     are provably distinct, so scatter == assignment.
//   g_esrc[slot] = src node id.
// Convs use a CHANNEL PERMUTATION of the S/K axis: S position p holds channel
//   6*(p&15)+(p>>4)  (conv3, CIN=96) / 2*(p&15)+(p>>4) (conv1/2, CIN=32).
// => phase-1 A-gather for lane m = ONE contiguous 12B (resp 4B) load from the
//   src row instead of 6 (resp 2) strided ushort loads. Weight packing
//   (prep_ws/prep_w3) applies the same permutation; writeback and phase 2
//   operate on positions and are unchanged.
// Phase 1 per 16-edge chunk: stage 16 dense basis rows (1 uint4/lane,
//   coalesced) + srcs into LDS, s_waitcnt(0) (r15 flake), then per (lane,j):
//   1 ds_read_b32 (src, broadcast) + 1 ds_read_b32 (basis pair) + 1 contiguous
//   A-load + pack + MFMA scatter-GEMM (K-slot = quad*8+j <-> edge j*4+quad).
// Phase 2: dense MFMA GEMM vs packed weights (conv3: K=2688 split 4-way over
//   waves, LDS reduction; kq=3 waves own root tiles + epilogue).
// Scan: two-level parallel (196-block partial + top + add).

#define EPS 1e-5f
#define MAXN 50176
#define MAXE 401408
#define SP2 904    // bf16 elems per S row (conv1/2): 864 spline + 32 root + 8 pad
#define SP3 2696   // bf16 elems per S row (conv3): 2592 spline + 96 root + 8 pad

typedef __attribute__((ext_vector_type(8))) short short8;
typedef __attribute__((ext_vector_type(4))) float floatx4;

__device__ int             g_deg[MAXN];
__device__ int             g_offs[MAXN + 1];
__device__ int             g_cursor[MAXN];
__device__ int             g_bsum[256];
__device__ int             g_esrc[MAXE];
__device__ __align__(16) uint4 g_ebas[MAXE * 4];   // interleaved 32-bin rows
__device__ __align__(16) __hip_bfloat16 g_h0[MAXN * 32];
__device__ __align__(16) __hip_bfloat16 g_h1[MAXN * 32];
__device__ __align__(16) __hip_bfloat16 g_h2[MAXN * 64];
__device__ __align__(16) __hip_bfloat16 g_h3[MAXN * 96];
__device__ __align__(16) __hip_bfloat16 g_Wp1[28672];
__device__ __align__(16) __hip_bfloat16 g_Wp2[57344];
__device__ __align__(16) __hip_bfloat16 g_Wp3[86016];
__device__ float           g_stats[128];
__device__ int             g_isbf16;

__device__ __forceinline__ float loadf(const void* p, int i, bool bf)
{
    return bf ? (float)((const __hip_bfloat16*)p)[i] : ((const float*)p)[i];
}
__device__ __forceinline__ float bf16f(unsigned int u)
{
    return __uint_as_float(u << 16);
}
__device__ __forceinline__ unsigned short bfbits(float f)
{
    union { __hip_bfloat16 h; unsigned short u; } cv;
    cv.h = __float2bfloat16(f);
    return cv.u;
}

// ---------------- K1: zero-init scratch + wire dtype detect ----------------
__global__ void init_detect(const unsigned int* __restrict__ x, int n)
{
    int i = blockIdx.x * blockDim.x + threadIdx.x;
    if (blockIdx.x == 0 && threadIdx.x < 64) {
        int lane = threadIdx.x;
        int cnt = 0;
        for (int k = lane; k < 256; k += 64) {
            unsigned int lo = x[k] & 0xFFFFu;
            int ex = (int)((lo >> 7) & 0xFFu);
            if (lo == 0u || (ex >= 96 && ex <= 140)) cnt++;
        }
#pragma unroll
        for (int o = 1; o < 64; o <<= 1) cnt += __shfl_xor(cnt, o, 64);
        if (lane == 0) g_isbf16 = (cnt >= 200) ? 1 : 0;
    }
    if (i < n) { g_deg[i] = 0; g_cursor[i] = 0; }
    if (i < 128) g_stats[i] = 0.0f;
}

// ---------------- weight pack helpers (device) ----------------
// K axis = positions; position p within a 32-wide bin row holds channel
// 2*(p&15) + (p>>4)  (the conv1/2 A-load permutation).
template <int COUT>
__device__ __forceinline__ void prep_ws_dev(const void* W, const void* root,
                                            __hip_bfloat16* Wp, int t, bool bf)
{
    int j = t & 7;
    int lane = (t >> 3) & 63;
    int rest = t >> 9;
    int kk = rest % 28;
    int nt = rest / 28;
    int k = kk * 32 + (lane >> 4) * 8 + j;   // physical K position
    int o = nt * 16 + (lane & 15);
    float v;
    if (k < 864) {
        int bin = k >> 5, p = k & 31;
        int ch = 2 * (p & 15) + (p >> 4);
        v = loadf(W, (bin * 32 + ch) * COUT + o, bf);
    } else {
        int p = k - 864;
        int ch = 2 * (p & 15) + (p >> 4);
        v = loadf(root, ch * COUT + o, bf);
    }
    Wp[t] = __float2bfloat16(v);
}

// conv3: position p within a 96-wide bin row holds channel 6*(p&15)+(p>>4).
// Channels 67..95 are zero (h3 pads 64 BN-ELU ch + 3 pos ch to 96).
__device__ __forceinline__ void prep_w3_dev(const void* W, const void* root,
                                            __hip_bfloat16* Wp, int t, bool bf)
{
    const int KB = 84;
    int j = t & 7;
    int lane = (t >> 3) & 63;
    int rest = t >> 9;          // < 168
    int kk = rest % KB;         // 0..83
    int nt = rest / KB;         // 0..1
    int k = kk * 32 + (lane >> 4) * 8 + j;   // physical K position 0..2687
    int o = nt * 16 + (lane & 15);           // 0..31
    float v = 0.0f;
    if (k < 2592) {
        int bin = k / 96;
        int p = k - bin * 96;
        int ch = 6 * (p & 15) + (p >> 4);
        if (ch < 67) v = loadf(W, (bin * 67 + ch) * 32 + o, bf);
    } else {
        int p = k - 2592;
        int ch = 6 * (p & 15) + (p >> 4);
        if (ch < 67) v = loadf(root, ch * 32 + o, bf);
    }
    Wp[t] = __float2bfloat16(v);
}

// ---------------- K2: degree count + cast x + pack all weights ----------------
__global__ void misc_kernel(const int* __restrict__ dst, const void* __restrict__ x,
                            const void* W1, const void* r1,
                            const void* W2, const void* r2,
                            const void* W3, const void* r3, int E, int N)
{
    int t = blockIdx.x * blockDim.x + threadIdx.x;
    const bool bf = (g_isbf16 != 0);
    if (t < E) { atomicAdd(&g_deg[dst[t]], 1); return; }
    t -= E;
    int nx = N * 32;
    if (t < nx) { g_h0[t] = __float2bfloat16(loadf(x, t, bf)); return; }
    t -= nx;
    if (t < 28672) { prep_ws_dev<32>(W1, r1, g_Wp1, t, bf); return; }
    t -= 28672;
    if (t < 57344) { prep_ws_dev<64>(W2, r2, g_Wp2, t, bf); return; }
    t -= 57344;
    if (t < 86016) { prep_w3_dev(W3, r3, g_Wp3, t, bf); return; }
}

// ---------------- K3a: per-block scan (256 elems/block) ----------------
__global__ void scan_blk(int n)
{
    __shared__ int buf[256];
    int tid = threadIdx.x;
    int i = blockIdx.x * 256 + tid;
    int v = (i < n) ? g_deg[i] : 0;
    buf[tid] = v;
    __syncthreads();
    for (int o = 1; o < 256; o <<= 1) {
        int t = (tid >= o) ? buf[tid - o] : 0;
        __syncthreads();
        buf[tid] += t;
        __syncthreads();
    }
    if (i < n) g_offs[i] = buf[tid] - v;   // block-local exclusive
    if (tid == 255) g_bsum[blockIdx.x] = buf[255];
}

// ---------------- K3b: scan of block sums (1 block; nb <= 256) ----------------
__global__ void scan_top(int nb, int n)
{
    __shared__ int buf[256];
    int tid = threadIdx.x;
    int v = (tid < nb) ? g_bsum[tid] : 0;
    buf[tid] = v;
    __syncthreads();
    for (int o = 1; o < 256; o <<= 1) {
        int t = (tid >= o) ? buf[tid - o] : 0;
        __syncthreads();
        buf[tid] += t;
        __syncthreads();
    }
    if (tid < nb) g_bsum[tid] = buf[tid] - v;   // exclusive
    if (tid == nb - 1) g_offs[n] = buf[tid];    // total = E
}

// ---------------- K3c: add block offsets ----------------
__global__ void scan_add(int n)
{
    int i = blockIdx.x * 256 + threadIdx.x;
    if (i < n) g_offs[i] += g_bsum[i >> 8];
}

// ---------------- K4: basis + CSR fill (interleaved 64-B basis rows) -------
__global__ void basis_fill(const void* __restrict__ attr,
                           const int* __restrict__ src,
                           const int* __restrict__ dst, int E)
{
    int e = blockIdx.x * blockDim.x + threadIdx.x;
    if (e >= E) return;
    const bool bf = (g_isbf16 != 0);
    float f[3];
    int lo[3];
#pragma unroll
    for (int d = 0; d < 3; ++d) {
        float a = loadf(attr, e * 3 + d, bf);
        float s = a * 3.0f;
        float l = floorf(s);
        lo[d] = (int)l;
        f[d] = s - l;
    }
    const int p3[3] = {1, 3, 9};
    int wx8[8];
    unsigned short bb[8];
#pragma unroll
    for (int b = 0; b < 8; ++b) {
        float w = 1.0f;
        int id = 0;
#pragma unroll
        for (int d = 0; d < 3; ++d) {
            int bit = (b >> d) & 1;
            w *= bit ? f[d] : (1.0f - f[d]);
            id += ((lo[d] + bit) % 3) * p3[d];
        }
        wx8[b] = id;
        bb[b] = bfbits(w);
    }
    // densify, pair-interleaved: u32 word i = (bin i | bin i+16 << 16)
    unsigned wds[16];
#pragma unroll
    for (int i = 0; i < 16; ++i) {
        unsigned w = 0;
#pragma unroll
        for (int b = 0; b < 8; ++b) {
            if (wx8[b] == i)      w |= (unsigned)bb[b];
            if (wx8[b] == i + 16) w |= (unsigned)bb[b] << 16;
        }
        wds[i] = w;
    }
    int d = dst[e];
    int p = atomicAdd(&g_cursor[d], 1);
    int slot = g_offs[d] + p;
    uint4* out4 = &g_ebas[(size_t)slot * 4];
    out4[0] = make_uint4(wds[0],  wds[1],  wds[2],  wds[3]);
    out4[1] = make_uint4(wds[4],  wds[5],  wds[6],  wds[7]);
    out4[2] = make_uint4(wds[8],  wds[9],  wds[10], wds[11]);
    out4[3] = make_uint4(wds[12], wds[13], wds[14], wds[15]);
    g_esrc[slot] = src[e];
}

// ---------------- fused conv (CIN=32), 8 nodes / 512 thr ----------------
// IN_SEL: 0 = g_h0, 1 = g_h1.  OUT_SEL: 1 = g_h1 (+ELU), 2 = g_h2 (raw).
template <int COUT, bool ELU, int IN_SEL, int OUT_SEL>
__global__ __launch_bounds__(512, 8) void fused_conv(const void* __restrict__ bias,
                                                     int N)
{
    __shared__ unsigned short Sb[8 * SP2];
    __shared__ __align__(16) unsigned basb[8][16][16];
    __shared__ int ssrc[8][16];
    __shared__ float invd[8];
    int tid = threadIdx.x, wid = tid >> 6, lane = tid & 63;
    int nbase = blockIdx.x * 8;
    const bool bf = (g_isbf16 != 0);
    const unsigned short* xptr = (IN_SEL == 0) ? (const unsigned short*)g_h0
                                               : (const unsigned short*)g_h1;
    const __hip_bfloat16* Wp = (COUT == 32) ? g_Wp1 : g_Wp2;

    int n = nbase + wid;
    int m = lane & 15, quad = lane >> 4;

    // ---- phase 1: wave wid builds S row for its node via MFMA scatter-GEMM ----
    if (n < N) {
        int e0 = g_offs[n], e1 = g_offs[n + 1];
        floatx4 C00 = {}, C01 = {}, C10 = {}, C11 = {};
        for (int base = e0; base < e1; base += 16) {
            int cnt = e1 - base; if (cnt > 16) cnt = 16;
            {   // stage 16 interleaved basis rows (64 B each) + src ids
                int es = lane >> 2, part = lane & 3;
                uint4 v = make_uint4(0, 0, 0, 0);
                if (es < cnt) v = g_ebas[(size_t)(base + es) * 4 + part];
                *(uint4*)&basb[wid][es][part * 4] = v;
                if (lane < 16)
                    ssrc[wid][lane] = (lane < cnt) ? g_esrc[base + lane] : 0;
            }
            // drain this wave's DS writes before cross-lane read-back (r15)
            __builtin_amdgcn_s_waitcnt(0);
            int jmax = (cnt + 3) >> 2;   // wave-uniform; zero rows beyond cnt
            unsigned a0w[4] = {0, 0, 0, 0}, a1w[4] = {0, 0, 0, 0};
            unsigned b0w[4] = {0, 0, 0, 0}, b1w[4] = {0, 0, 0, 0};
#pragma unroll
            for (int j = 0; j < 4; ++j) {
                if (j >= jmax) break;
                // K-permutation: fragment slot (quad, j) holds edge j*4+quad.
                int kidx = j * 4 + quad;
                int sn = ssrc[wid][kidx];
                unsigned pw = basb[wid][kidx][m];      // (bin m | bin m+16)
                // channels (2m, 2m+1) = tiles (0,1) row m, one dword
                unsigned hw = *((const unsigned*)xptr + (size_t)sn * 16 + m);
                unsigned sh = 16 * (j & 1);
                a0w[j >> 1] |= (hw & 0xFFFFu) << sh;
                a1w[j >> 1] |= (hw >> 16) << sh;
                b0w[j >> 1] |= (pw & 0xFFFFu) << sh;
                b1w[j >> 1] |= (pw >> 16) << sh;
            }
            union U { unsigned w[4]; short8 v; } A0, A1, B0, B1;
#pragma unroll
            for (int q = 0; q < 4; ++q) {
                A0.w[q] = a0w[q]; A1.w[q] = a1w[q];
                B0.w[q] = b0w[q]; B1.w[q] = b1w[q];
            }
            C00 = __builtin_amdgcn_mfma_f32_16x16x32_bf16(A0.v, B0.v, C00, 0, 0, 0);
            C01 = __builtin_amdgcn_mfma_f32_16x16x32_bf16(A0.v, B1.v, C01, 0, 0, 0);
            C10 = __builtin_amdgcn_mfma_f32_16x16x32_bf16(A1.v, B0.v, C10, 0, 0, 0);
            C11 = __builtin_amdgcn_mfma_f32_16x16x32_bf16(A1.v, B1.v, C11, 0, 0, 0);
        }
        // writeback (positions, unchanged): C[mt][nt] lane: col=m (bin-in-tile),
        // rows quad*4+r -> S[bin*32 + mt*16 + quad*4 + r]
        unsigned short* Srow = Sb + wid * SP2;
        {
            floatx4 Cf[4] = {C00, C01, C10, C11};
#pragma unroll
            for (int f = 0; f < 4; ++f) {
                int mt = f >> 1, nt = f & 1;
                int bin = nt * 16 + m;
                if (bin < 27) {
                    union { unsigned short h[4]; uint2 u; } pk;
#pragma unroll
                    for (int r = 0; r < 4; ++r) pk.h[r] = bfbits(Cf[f][r]);
                    *(uint2*)(Srow + bin * 32 + mt * 16 + quad * 4) = pk.u;
                }
            }
        }
        if (lane < 32) {
            int ch = 2 * (lane & 15) + (lane >> 4);
            Srow[864 + lane] = xptr[(size_t)n * 32 + ch];
        }
        if (lane == 0) {
            int deg = e1 - e0;
            invd[wid] = 1.0f / (float)(deg < 1 ? 1 : deg);
        }
    }
    __syncthreads();

    // ---- phase 2: wave w = col-tile w of GEMM 16 x 896 @ 896 x COUT ----
    if (wid * 16 < COUT) {
        int mrow = m & 7;   // 8 nodes; rows 8..15 duplicate (discarded below)
        const unsigned short* Ab = Sb + mrow * SP2 + quad * 8;
        floatx4 accS = {}, accR = {};
#pragma unroll
        for (int kk = 0; kk < 28; ++kk) {
            short8 a = *(const short8*)(Ab + kk * 32);
            const short* bp = (const short*)Wp +
                ((size_t)(wid * 28 + kk) * 64 + lane) * 8;
            short8 b = *(const short8*)bp;
            if (kk < 27) accS = __builtin_amdgcn_mfma_f32_16x16x32_bf16(a, b, accS, 0, 0, 0);
            else         accR = __builtin_amdgcn_mfma_f32_16x16x32_bf16(a, b, accR, 0, 0, 0);
        }
        int o = wid * 16 + m;
        float bval = loadf(bias, o, bf);
#pragma unroll
        for (int r = 0; r < 4; ++r) {
            int slot = quad * 4 + r;
            if (slot >= 8) continue;
            int nn = nbase + slot;
            if (nn >= N) continue;
            float v = accS[r] * invd[slot] + accR[r] + bval;
            if (ELU) v = v > 0.0f ? v : expm1f(v);
            if (OUT_SEL == 1) g_h1[nn * 32 + o] = __float2bfloat16(v);
            else              g_h2[nn * 64 + o] = __float2bfloat16(v);
        }
    }
}

// ---------------- fused conv3 (CIN=96 from g_h3, COUT=32 to out) ----------------
// Phase 1: 6 A-tiles x 2 B-tiles; A-gather = one contiguous 12B load per
// (lane, j) via the channel permutation. Phase 2: 16 x 2688 @ 2688 x 32 GEMM,
// K split 4-way over waves (21 K-tiles each), LDS reduction; kq==3 waves hold
// root tiles (kk 81..83, never invd-scaled) and run the epilogue + store.
__global__ __launch_bounds__(512, 4) void fused_conv3(const void* __restrict__ bias,
                                                      void* __restrict__ out_ext,
                                                      int N)
{
    __shared__ __align__(16) unsigned short Sb[8 * SP3];   // 43136 B
    __shared__ __align__(16) union {
        struct { unsigned bas[8][16][16]; int src[8][16]; } s1;  // 8704 B
        float red[6][64][4];                                     // 6144 B
    } u;
    __shared__ float invd[8];
    int tid = threadIdx.x, wid = tid >> 6, lane = tid & 63;
    int nbase = blockIdx.x * 8;
    const bool bf = (g_isbf16 != 0);
    const unsigned short* xptr = (const unsigned short*)g_h3;

    int n = nbase + wid;
    int m = lane & 15, quad = lane >> 4;

    // ---- phase 1: wave wid builds S row (27 bins x 96 pos) via MFMA scatter ----
    if (n < N) {
        int e0 = g_offs[n], e1 = g_offs[n + 1];
        floatx4 C[6][2];
#pragma unroll
        for (int t = 0; t < 6; ++t) {
            C[t][0] = (floatx4){0.f, 0.f, 0.f, 0.f};
            C[t][1] = (floatx4){0.f, 0.f, 0.f, 0.f};
        }
        for (int base = e0; base < e1; base += 16) {
            int cnt = e1 - base; if (cnt > 16) cnt = 16;
            {   // stage 16 interleaved basis rows + src ids
                int es = lane >> 2, part = lane & 3;
                uint4 v = make_uint4(0, 0, 0, 0);
                if (es < cnt) v = g_ebas[(size_t)(base + es) * 4 + part];
                *(uint4*)&u.s1.bas[wid][es][part * 4] = v;
                if (lane < 16)
                    u.s1.src[wid][lane] = (lane < cnt) ? g_esrc[base + lane] : 0;
            }
            __builtin_amdgcn_s_waitcnt(0);   // r15: drain DS writes
            int jmax = (cnt + 3) >> 2;
            unsigned aw[6][4] = {{0, 0, 0, 0}, {0, 0, 0, 0}, {0, 0, 0, 0},
                                 {0, 0, 0, 0}, {0, 0, 0, 0}, {0, 0, 0, 0}};
            unsigned b0w[4] = {0, 0, 0, 0}, b1w[4] = {0, 0, 0, 0};
#pragma unroll
            for (int j = 0; j < 4; ++j) {
                if (j >= jmax) break;
                int kidx = j * 4 + quad;
                int sn = u.s1.src[wid][kidx];
                unsigned pw = u.s1.bas[wid][kidx][m];  // (bin m | bin m+16)
                // channels 6m..6m+5 = tiles 0..5 row m: 3 contiguous dwords
                const unsigned* hp = (const unsigned*)xptr + (size_t)sn * 48 + m * 3;
                unsigned h0 = hp[0], h1 = hp[1], h2 = hp[2];
                unsigned sh = 16 * (j & 1);
                int r = j >> 1;
                aw[0][r] |= (h0 & 0xFFFFu) << sh;
                aw[1][r] |= (h0 >> 16) << sh;
                aw[2][r] |= (h1 & 0xFFFFu) << sh;
                aw[3][r] |= (h1 >> 16) << sh;
                aw[4][r] |= (h2 & 0xFFFFu) << sh;
                aw[5][r] |= (h2 >> 16) << sh;
                b0w[r] |= (pw & 0xFFFFu) << sh;
                b1w[r] |= (pw >> 16) << sh;
            }
            union U { unsigned w[4]; short8 v; } A, B0, B1;
#pragma unroll
            for (int q = 0; q < 4; ++q) { B0.w[q] = b0w[q]; B1.w[q] = b1w[q]; }
#pragma unroll
            for (int t = 0; t < 6; ++t) {
#pragma unroll
                for (int q = 0; q < 4; ++q) A.w[q] = aw[t][q];
                C[t][0] = __builtin_amdgcn_mfma_f32_16x16x32_bf16(A.v, B0.v, C[t][0], 0, 0, 0);
                C[t][1] = __builtin_amdgcn_mfma_f32_16x16x32_bf16(A.v, B1.v, C[t][1], 0, 0, 0);
            }
        }
        // writeback (positions, unchanged): C[t][nt] lane: col=m (bin-in-tile),
        // rows quad*4+r -> S[bin*96 + t*16 + quad*4 + r]
        unsigned short* Srow = Sb + wid * SP3;
#pragma unroll
        for (int t = 0; t < 6; ++t) {
#pragma unroll
            for (int ntile = 0; ntile < 2; ++ntile) {
                int bin = ntile * 16 + m;
                if (bin < 27) {
                    union { unsigned short h[4]; uint2 uu; } pk;
#pragma unroll
                    for (int r = 0; r < 4; ++r) pk.h[r] = bfbits(C[t][ntile][r]);
                    *(uint2*)(Srow + bin * 96 + t * 16 + quad * 4) = pk.uu;
                }
            }
        }
        for (int p = lane; p < 96; p += 64) {
            int ch = 6 * (p & 15) + (p >> 4);
            Srow[2592 + p] = xptr[(size_t)n * 96 + ch];
        }
        if (lane == 0) {
            int deg = e1 - e0;
            invd[wid] = 1.0f / (float)(deg < 1 ? 1 : deg);
        }
    }
    __syncthreads();

    // ---- phase 2: GEMM 16 x 2688 @ 2688 x 32; wave = (col-tile nt, K-quarter kq)
    int nt = wid & 1, kq = wid >> 1;
    int mrow = m & 7;   // 8 nodes; rows 8..15 duplicate (discarded in epilogue)
    const unsigned short* Ab = Sb + mrow * SP3 + quad * 8;
    floatx4 accS = {}, accR = {};
    {
        int kbeg = kq * 21, kend = kbeg + 21;
        int ksplit = (kend < 81) ? kend : 81;   // root tiles are kk 81..83 (kq==3)
        for (int kk = kbeg; kk < ksplit; ++kk) {
            short8 a = *(const short8*)(Ab + kk * 32);
            const short* bp = (const short*)g_Wp3 +
                ((size_t)(nt * 84 + kk) * 64 + lane) * 8;
            short8 b = *(const short8*)bp;
            accS = __builtin_amdgcn_mfma_f32_16x16x32_bf16(a, b, accS, 0, 0, 0);
        }
        for (int kk = ksplit; kk < kend; ++kk) {
            short8 a = *(const short8*)(Ab + kk * 32);
            const short* bp = (const short*)g_Wp3 +
                ((size_t)(nt * 84 + kk) * 64 + lane) * 8;
            short8 b = *(const short8*)bp;
            accR = __builtin_amdgcn_mfma_f32_16x16x32_bf16(a, b, accR, 0, 0, 0);
        }
    }
    if (kq < 3)
        *(floatx4*)&u.red[wid][lane][0] = accS;
    __syncthreads();
    if (kq == 3) {
#pragma unroll
        for (int w = 0; w < 3; ++w)
            accS += *(const floatx4*)&u.red[2 * w + nt][lane][0];
        int o = nt * 16 + m;
        float bval = loadf(bias, o, bf);
#pragma unroll
        for (int r = 0; r < 4; ++r) {
            int slot = quad * 4 + r;
            if (slot >= 8) continue;
            int nn = nbase + slot;
            if (nn >= N) continue;
            float v = accS[r] * invd[slot] + accR[r] + bval;
            if (bf) ((__hip_bfloat16*)out_ext)[nn * 32 + o] = __float2bfloat16(v);
            else    ((float*)out_ext)[nn * 32 + o] = v;
        }
    }
}

// ---------------- BN stats (reads g_h2) ----------------
__global__ void bn_reduce(int n)
{
    int tid = threadIdx.x;
    int c = tid & 63;
    int r = tid >> 6;
    float s = 0.0f, s2 = 0.0f;
    for (int i = blockIdx.x * 4 + r; i < n; i += gridDim.x * 4) {
        float v = (float)g_h2[i * 64 + c];
        s += v; s2 += v * v;
    }
    __shared__ float b1s[256], b2s[256];
    b1s[tid] = s; b2s[tid] = s2;
    __syncthreads();
    if (r == 0) {
        s  = b1s[c] + b1s[c + 64] + b1s[c + 128] + b1s[c + 192];
        s2 = b2s[c] + b2s[c + 64] + b2s[c + 128] + b2s[c + 192];
        atomicAdd(&g_stats[c], s);
        atomicAdd(&g_stats[64 + c], s2);
    }
}

// ---------------- h3 = [elu(bn(h2)), pos, 0-pad] (96 ch), coef inline -------
__global__ void h3_build(const void* __restrict__ pos,
                         const void* __restrict__ gamma,
                         const void* __restrict__ beta, int N)
{
    __shared__ float cf[128];
    int t = threadIdx.x;
    const bool bf = (g_isbf16 != 0);
    if (t < 64) {
        float inv_n = 1.0f / (float)N;
        float mu = g_stats[t] * inv_n;
        float var = g_stats[64 + t] * inv_n - mu * mu;
        float A = rsqrtf(var + EPS) * loadf(gamma, t, bf);
        cf[t] = A;
        cf[64 + t] = loadf(beta, t, bf) - mu * A;
    }
    __syncthreads();
    int idx = blockIdx.x * blockDim.x + t;
    if (idx >= N * 96) return;
    int n = idx / 96, ch = idx - n * 96;
    float v;
    if (ch < 64) {
        float h = (float)g_h2[n * 64 + ch];
        v = h * cf[ch] + cf[64 + ch];
        v = v > 0.0f ? v : expm1f(v);
    } else if (ch < 67) {
        v = loadf(pos, n * 3 + (ch - 64), bf);
    } else {
        v = 0.0f;
    }
    g_h3[(size_t)n * 96 + ch] = __float2bfloat16(v);
}

extern "C" void kernel_launch(void* const* d_in, const int* in_sizes, int n_in,
                              void* d_out, int out_size, void* d_ws, size_t ws_size,
                              hipStream_t stream)
{
    const void* x      = d_in[0];
    const int*  eindex = (const int*)d_in[1];
    const void* eattr  = d_in[2];
    const void* pos    = d_in[3];
    const void* W1     = d_in[4];
    const void* root1  = d_in[5];
    const void* b1     = d_in[6];
    const void* W2     = d_in[7];
    const void* root2  = d_in[8];
    const void* b2     = d_in[9];
    const void* gamma  = d_in[10];
    const void* beta   = d_in[11];
    const void* W3     = d_in[12];
    const void* root3  = d_in[13];
    const void* b3     = d_in[14];
    (void)d_ws; (void)ws_size; (void)n_in; (void)out_size;

    const int N = in_sizes[0] / 32;
    const int E = in_sizes[1] / 2;
    const int* srcp = eindex;
    const int* dstp = eindex + E;

    init_detect<<<(N + 255) / 256, 256, 0, stream>>>((const unsigned int*)x, N);
    {
        int tot = E + N * 32 + 28672 + 57344 + 86016;
        misc_kernel<<<(tot + 255) / 256, 256, 0, stream>>>(
            dstp, x, W1, root1, W2, root2, W3, root3, E, N);
    }
    // two-level parallel scan
    int nb = (N + 255) / 256;   // 196 <= 256
    scan_blk<<<nb, 256, 0, stream>>>(N);
    scan_top<<<1, 256, 0, stream>>>(nb, N);
    scan_add<<<nb, 256, 0, stream>>>(N);
    basis_fill<<<(E + 255) / 256, 256, 0, stream>>>(eattr, srcp, dstp, E);

    int nb8 = (N + 7) / 8;
    fused_conv<32, true, 0, 1><<<nb8, 512, 0, stream>>>(b1, N);
    fused_conv<64, false, 1, 2><<<nb8, 512, 0, stream>>>(b2, N);
    bn_reduce<<<120, 256, 0, stream>>>(N);
    h3_build<<<(N * 96 + 255) / 256, 256, 0, stream>>>(pos, gamma, beta, N);
    fused_conv3<<<nb8, 512, 0, stream>>>(b3, d_out, N);
}